// Round 1
// baseline (341.533 us; speedup 1.0000x reference)
//
#include <hip/hip_runtime.h>
#include <math.h>

#define EPS 1e-9f

constexpr int Bn = 1024, Dn = 512, Un = 512;
constexpr int BM = 64;      // rows of B per block (4x4 per thread)
constexpr int BU = 64;      // cols of U per block
constexpr int DK = 16;      // k-chunk staged in LDS (16KB/block)
constexpr int NTILES = (Bn / BM) * (Un / BU);   // 128 output tiles

typedef float v4f __attribute__((ext_vector_type(4)));

// Split-K semaphores: zero-initialized (.bss); last-arriving block resets its
// slot to 0, so the invariant "all zeros between launches" survives graph replay.
__device__ int tile_cnt[NTILES];

// XOR swizzle for sL columns (proven: conflicts -> 0). Multiples of 8,
// preserves b128 alignment of 4-float groups.
__device__ __forceinline__ int swz(int d) { return ((d >> 2) & 3) << 3; }

// MODE 0: atomicAdd directly into out (small-ws fallback; out pre-zeroed)
// MODE 1: ws partials + in-kernel fused tail reduction (semaphore)
template <int SPLITD, int MODE>
__global__ __launch_bounds__(256, 4) void power_layer(
    const float* __restrict__ x, const float* __restrict__ w,
    const float* __restrict__ p, const float* __restrict__ bias,
    float* __restrict__ outp, float* __restrict__ wsp)
{
    constexpr int DPB    = Dn / SPLITD;
    constexpr int NCHUNK = DPB / DK;

    __shared__ float sL[DK][BM];   // sign(neg)*(log2|x+eps|+64), swizzled cols
    __shared__ float sP[DK][BU];   // p
    __shared__ float sW[DK][BU];   // w
    __shared__ float sWX[DK][BU];  // odd(p) ? -w : w

    const int tid = threadIdx.x;
    const int tx  = tid & 15;
    const int ty  = tid >> 4;
    const int tx4 = tx * 4;
    const int ty4 = ty * 4;
    const int ub = blockIdx.x * BU;
    const int bb = blockIdx.y * BM;
    const int d0 = blockIdx.z * DPB;

    // staging thread->element maps (chunk-invariant)
    const int xr  = tid >> 2;          // 0..63  (row for x tile)
    const int xdq = (tid & 3) << 2;    // 0,4,8,12 (d quad for x tile)
    const int pd  = tid >> 4;          // 0..15  (d for p/w tile)
    const int puq = (tid & 15) << 2;   // 0..60  (u quad for p/w tile)

    float4 xv, pv, wv;                 // global->reg prefetch (software pipeline)

    auto load_chunk = [&](int ch) {
        const int db = d0 + ch * DK;
        xv = *reinterpret_cast<const float4*>(&x[(size_t)(bb + xr) * Dn + db + xdq]);
        const size_t gi = (size_t)(db + pd) * Un + ub + puq;
        pv = *reinterpret_cast<const float4*>(&p[gi]);
        wv = *reinterpret_cast<const float4*>(&w[gi]);
    };

    auto stage_chunk = [&]() {
        const float* xs = reinterpret_cast<const float*>(&xv);
        #pragma unroll
        for (int j = 0; j < 4; ++j) {
            const float xe = xs[j] + EPS;
            const float La = __builtin_amdgcn_logf(fabsf(xe)) + 64.0f;
            const int dd = xdq + j;
            sL[dd][xr ^ swz(dd)] = (xe < 0.0f) ? -La : La;
        }
        const float* ps  = reinterpret_cast<const float*>(&pv);
        const float* wsv = reinterpret_cast<const float*>(&wv);
        float4 wxv;
        float* wxs = reinterpret_cast<float*>(&wxv);
        #pragma unroll
        for (int j = 0; j < 4; ++j) {
            const bool odd = (fmodf(ps[j], 2.0f) != 0.0f);
            wxs[j] = odd ? -wsv[j] : wsv[j];
        }
        *reinterpret_cast<float4*>(&sP[pd][puq])  = pv;
        *reinterpret_cast<float4*>(&sW[pd][puq])  = wv;
        *reinterpret_cast<float4*>(&sWX[pd][puq]) = wxv;
    };

    v4f acc[4] = {};   // 4 rows x 4 cols per thread

    load_chunk(0);
    stage_chunk();
    __syncthreads();

    for (int ch = 0; ch < NCHUNK; ++ch) {
        // issue next chunk's global loads now; latency hides under 16 d-iters
        if (ch + 1 < NCHUNK) load_chunk(ch + 1);

        #pragma unroll 2
        for (int d = 0; d < DK; ++d) {
            const v4f Lv = *reinterpret_cast<const v4f*>(&sL[d][ty4 ^ swz(d)]);
            const v4f Pv = *reinterpret_cast<const v4f*>(&sP[d][tx4]);

            // sign(x) selects WHICH array we read (1 cmp + 1 cndmask on the
            // address per row) instead of 4 per-element cndmasks per row.
            // Worst case 2-way LDS conflict across ty lanes = free.
            float Ld[4];
            const float* wp[4];
            #pragma unroll
            for (int r = 0; r < 4; ++r) {
                Ld[r] = fabsf(Lv[r]) - 64.0f;
                wp[r] = (Lv[r] < 0.0f) ? &sWX[d][tx4] : &sW[d][tx4];
            }
            v4f Wsel[4];
            #pragma unroll
            for (int r = 0; r < 4; ++r)
                Wsel[r] = *reinterpret_cast<const v4f*>(wp[r]);

            // batch all 16 independent exps
            v4f e[4];
            #pragma unroll
            for (int r = 0; r < 4; ++r) {
                const v4f t = Pv * Ld[r];          // v_pk_mul_f32 x2
                #pragma unroll
                for (int c = 0; c < 4; ++c)
                    e[r][c] = __builtin_amdgcn_exp2f(t[c]);
            }

            #pragma unroll
            for (int r = 0; r < 4; ++r)
                acc[r] = __builtin_elementwise_fma(Wsel[r], e[r], acc[r]);  // v_pk_fma x2
        }
        __syncthreads();
        if (ch + 1 < NCHUNK) {
            stage_chunk();          // regs (loaded above) -> LDS
            __syncthreads();
        }
    }

    if (MODE == 0) {
        if (blockIdx.z == 0) {
            const v4f bv = *reinterpret_cast<const v4f*>(&bias[ub + tx4]);
            #pragma unroll
            for (int r = 0; r < 4; ++r)
                acc[r] += bv;
        }
        #pragma unroll
        for (int r = 0; r < 4; ++r) {
            const int row = bb + ty4 + r;
            #pragma unroll
            for (int c = 0; c < 4; ++c)
                atomicAdd(&outp[(size_t)row * Un + ub + tx4 + c], acc[r][c]);
        }
        return;
    }

    // ---- MODE 1: write partial, then last-arriving z-block reduces the tile ----
    {
        float* dst = wsp + (((size_t)blockIdx.z * Bn + bb + ty4) * Un + ub + tx4);
        #pragma unroll
        for (int r = 0; r < 4; ++r)
            *reinterpret_cast<v4f*>(dst + (size_t)r * Un) = acc[r];
    }

    __threadfence();               // release our partial (agent scope: wb L1/L2)
    __syncthreads();               // all threads' stores fenced before arrive

    __shared__ int s_last;
    if (tid == 0) {
        const int tile = blockIdx.y * (Un / BU) + blockIdx.x;
        const int old = __hip_atomic_fetch_add(&tile_cnt[tile], 1,
                            __ATOMIC_ACQ_REL, __HIP_MEMORY_SCOPE_AGENT);
        s_last = (old == SPLITD - 1) ? 1 : 0;
        if (old == SPLITD - 1)     // self-clean for the next launch/replay
            __hip_atomic_store(&tile_cnt[tile], 0, __ATOMIC_RELAXED,
                               __HIP_MEMORY_SCOPE_AGENT);
    }
    __syncthreads();
    if (!s_last) return;
    __threadfence();               // acquire: invalidate stale L1/L2 lines before
                                   // reading other XCDs' partials

    const v4f bv = *reinterpret_cast<const v4f*>(&bias[ub + tx4]);
    v4f sum[4] = {bv, bv, bv, bv};
    const float* srcBase = wsp + ((size_t)(bb + ty4) * Un + ub + tx4);
    for (int z = 0; z < SPLITD; ++z) {
        const float* src = srcBase + (size_t)z * Bn * Un;
        #pragma unroll
        for (int r = 0; r < 4; ++r)
            sum[r] += *reinterpret_cast<const v4f*>(src + (size_t)r * Un);
    }
    float* dsto = outp + ((size_t)(bb + ty4) * Un + ub + tx4);
    #pragma unroll
    for (int r = 0; r < 4; ++r)
        *reinterpret_cast<v4f*>(dsto + (size_t)r * Un) = sum[r];
}

extern "C" void kernel_launch(void* const* d_in, const int* in_sizes, int n_in,
                              void* d_out, int out_size, void* d_ws, size_t ws_size,
                              hipStream_t stream) {
    const float* x = (const float*)d_in[0];
    const float* w = (const float*)d_in[1];
    const float* p = (const float*)d_in[2];
    const float* b = (const float*)d_in[3];
    float* out = (float*)d_out;
    float* wsf = (float*)d_ws;

    const size_t need16 = (size_t)16 * Bn * Un * sizeof(float);   // 32 MB
    const size_t need8  = (size_t)8  * Bn * Un * sizeof(float);   // 16 MB
    const dim3 blk(256);

    if (ws_size >= need16) {
        // 8 x 16 x 16 = 2048 blocks = exactly 8 blocks/CU (one resident round)
        power_layer<16, 1><<<dim3(Un / BU, Bn / BM, 16), blk, 0, stream>>>(x, w, p, b, out, wsf);
    } else if (ws_size >= need8) {
        power_layer<8, 1><<<dim3(Un / BU, Bn / BM, 8), blk, 0, stream>>>(x, w, p, b, out, wsf);
    } else {
        hipMemsetAsync(out, 0, (size_t)out_size * sizeof(float), stream);
        power_layer<8, 0><<<dim3(Un / BU, Bn / BM, 8), blk, 0, stream>>>(x, w, p, b, out, wsf);
    }
}